// Round 7
// baseline (83.801 us; speedup 1.0000x reference)
//
#include <hip/hip_runtime.h>
#include <hip/hip_fp16.h>
#include <math.h>
#include <stdint.h>

#define U 50
#define TT 100
#define BB 256

typedef _Float16 half2v __attribute__((ext_vector_type(2)));

// asm dot2 guarantees v_dot2_f32_f16 regardless of builtin availability.
__device__ __forceinline__ void dot2_asm(float& acc, uint32_t h2, uint32_t w2) {
    asm("v_dot2_f32_f16 %0, %1, %2, %0" : "+v"(acc) : "v"(h2), "v"(w2));
}

__device__ __forceinline__ float sigmoid_fast(float x) {
    return 1.0f / (1.0f + __expf(-x));
}
__device__ __forceinline__ float tanh_fast(float x) {
    float e = __expf(2.0f * x);
    return 1.0f - 2.0f / (e + 1.0f);
}
__device__ __forceinline__ float param_act(float x, float mn, float mx) {
    float scale = 0.5f * (mx - mn);
    return tanh_fast(x) * scale + mn + scale;
}

// One wave per batch element; lane l (<50) owns LSTM unit l. All heavy
// loop-invariant data (rec, kernel, bias) is staged ONCE into LDS and
// STREAMED with explicit ds_read each step -- the allocator has nothing
// big to rematerialize or spill (rounds 2-5 failure mode). h is exchanged
// through LDS broadcast. Single wave -> zero barriers.
__global__ __launch_bounds__(64, 1) void encoder_kernel(
    const float* __restrict__ x,        // (B,T,4)
    const float* __restrict__ state,    // (B,T,4)
    const float* __restrict__ kernel,   // (4,200)
    const float* __restrict__ rec,      // (50,200)
    const float* __restrict__ bias,     // (200,)
    const float* __restrict__ w_dv, const float* __restrict__ b_dv,
    const float* __restrict__ w_dt, const float* __restrict__ b_dt,
    const float* __restrict__ w_mj, const float* __restrict__ b_mj,
    const float* __restrict__ w_ma, const float* __restrict__ b_ma,
    const float* __restrict__ w_mi, const float* __restrict__ b_mi,
    float* __restrict__ out)            // act_seq (B*T) then idm (B*5)
{
    const int b = blockIdx.x;
    const int l = threadIdx.x;

    // wlds[j*64+l] = 4 gates' packed f16 pair j for column-lane l (25,600 B)
    __shared__ __align__(16) uint4  wlds[25 * 64];
    __shared__ __align__(16) float4 kclds[4 * 64];   // kclds[f*64+l] = {k[f][g*50+l]}g  (4,096 B)
    __shared__ __align__(16) float4 bzlds[64];       // {bias[g*50+l]}g                  (1,024 B)
    __shared__ __align__(16) _Float16 h16[64];       // h state, dword k = packed pair k
    __shared__ float idm[8];

    // ---- one-time staging (lanes 0..49) ----
    if (l < U) {
        for (int j = 0; j < 25; ++j) {
            uint4 w;
            uint32_t* wp = &w.x;
            #pragma unroll
            for (int g = 0; g < 4; ++g) {
                float r0 = rec[(2 * j) * 200 + g * U + l];
                float r1 = rec[(2 * j + 1) * 200 + g * U + l];
                half2v p; p.x = (_Float16)r0; p.y = (_Float16)r1;
                wp[g] = __builtin_bit_cast(uint32_t, p);
            }
            wlds[j * 64 + l] = w;
        }
        #pragma unroll
        for (int f = 0; f < 4; ++f) {
            float4 k4;
            k4.x = kernel[f * 200 + 0 * U + l];
            k4.y = kernel[f * 200 + 1 * U + l];
            k4.z = kernel[f * 200 + 2 * U + l];
            k4.w = kernel[f * 200 + 3 * U + l];
            kclds[f * 64 + l] = k4;
        }
        float4 b4;
        b4.x = bias[0 * U + l]; b4.y = bias[1 * U + l];
        b4.z = bias[2 * U + l]; b4.w = bias[3 * U + l];
        bzlds[l] = b4;
    }
    h16[l] = (_Float16)0.0f;
    // single wave: staging writes and loop reads are same-wave in-order; no barrier

    const float4* __restrict__ xb4 = (const float4*)(x + (size_t)b * TT * 4);
    const uint4* __restrict__ hq = (const uint4*)h16;
    const uint32_t* __restrict__ hd = (const uint32_t*)h16;

    float4 x4 = xb4[0];
    float c = 0.0f;

    // pipelined h fragment (zeros at t=0)
    uint32_t hvu[25];
    #pragma unroll
    for (int q = 0; q < 6; ++q) {
        uint4 v = hq[q];
        hvu[4 * q + 0] = v.x; hvu[4 * q + 1] = v.y;
        hvu[4 * q + 2] = v.z; hvu[4 * q + 3] = v.w;
    }
    hvu[24] = hd[24];

    for (int t = 0; t < TT; ++t) {
        float4 x4n = xb4[(t + 1 < TT) ? (t + 1) : t];  // prefetch

        // x-part, operands streamed from LDS (5 x ds_read_b128)
        float4 bz4 = bzlds[l];
        float4 k0 = kclds[0 * 64 + l];
        float4 k1 = kclds[1 * 64 + l];
        float4 k2 = kclds[2 * 64 + l];
        float4 k3 = kclds[3 * 64 + l];
        float zx0 = fmaf(x4.x, k0.x, fmaf(x4.y, k1.x, fmaf(x4.z, k2.x, fmaf(x4.w, k3.x, bz4.x))));
        float zx1 = fmaf(x4.x, k0.y, fmaf(x4.y, k1.y, fmaf(x4.z, k2.y, fmaf(x4.w, k3.y, bz4.y))));
        float zx2 = fmaf(x4.x, k0.z, fmaf(x4.y, k1.z, fmaf(x4.z, k2.z, fmaf(x4.w, k3.z, bz4.z))));
        float zx3 = fmaf(x4.x, k0.w, fmaf(x4.y, k1.w, fmaf(x4.z, k2.w, fmaf(x4.w, k3.w, bz4.w))));

        // recurrent GEMV: stream weights from LDS, 100 v_dot2_f32_f16
        float acc[8] = {0.f, 0.f, 0.f, 0.f, 0.f, 0.f, 0.f, 0.f};
        #pragma unroll
        for (int j = 0; j < 25; ++j) {
            uint4 w = wlds[j * 64 + l];        // ds_read_b128, imm offset j*1024
            const int s = (j & 1) * 4;
            dot2_asm(acc[s + 0], hvu[j], w.x);
            dot2_asm(acc[s + 1], hvu[j], w.y);
            dot2_asm(acc[s + 2], hvu[j], w.z);
            dot2_asm(acc[s + 3], hvu[j], w.w);
        }

        float zi = zx0 + acc[0] + acc[4];
        float zf = zx1 + acc[1] + acc[5];
        float zg = zx2 + acc[2] + acc[6];
        float zo = zx3 + acc[3] + acc[7];

        float ig = sigmoid_fast(zi);
        float fg = sigmoid_fast(zf);
        float gg = tanh_fast(zg);
        float og = sigmoid_fast(zo);
        c = fmaf(fg, c, ig * gg);
        float hnew = og * tanh_fast(c);
        if (l < U) h16[l] = (_Float16)hnew;

        // re-read h immediately (latency overlaps next step's x-part)
        #pragma unroll
        for (int q = 0; q < 6; ++q) {
            uint4 v = hq[q];
            hvu[4 * q + 0] = v.x; hvu[4 * q + 1] = v.y;
            hvu[4 * q + 2] = v.z; hvu[4 * q + 3] = v.w;
        }
        hvu[24] = hd[24];

        x4 = x4n;
        // no barrier: single wave, in-order LDS pipeline
    }

    // ---- 5 output heads (lanes 0..4) ----
    if (l < 5) {
        const float* w  = (l == 0) ? w_dv : (l == 1) ? w_dt :
                          (l == 2) ? w_mj : (l == 3) ? w_ma : w_mi;
        const float* bb = (l == 0) ? b_dv : (l == 1) ? b_dt :
                          (l == 2) ? b_mj : (l == 3) ? b_ma : b_mi;
        float s = bb[0];
        #pragma unroll
        for (int j = 0; j < U; ++j) s = fmaf((float)h16[j], w[j], s);
        float v;
        if (l == 0)      v = param_act(s, 15.0f, 35.0f);
        else if (l == 1) v = param_act(s, 0.5f, 3.0f);
        else if (l == 2) v = fmaxf(s, 0.0f);
        else if (l == 3) v = param_act(s, 0.5f, 3.0f);
        else             v = param_act(s, 0.5f, 4.0f);
        idm[l] = v;
        out[BB * TT + b * 5 + l] = v;
    }

    // ---- IDM physics over T ----
    const float desired_v    = idm[0];
    const float desired_tgap = idm[1];
    const float min_jamx     = idm[2];
    const float max_act      = idm[3];
    const float min_act      = idm[4];
    const float inv_tsab = 1.0f / (2.0f * sqrtf(max_act * min_act));
    const float inv_dv   = 1.0f / desired_v;

    const float4* __restrict__ sb4 = (const float4*)(state + (size_t)b * TT * 4);
    for (int t = l; t < TT; t += 64) {
        float4 s4 = sb4[t];
        float vel = s4.x;
        float dv  = s4.z;
        float dx  = s4.w;
        float dgap = fmaf(desired_tgap, vel, fmaf(vel * dv, inv_tsab, min_jamx));
        float r1 = vel * inv_dv;
        r1 = r1 * r1;
        r1 = r1 * r1;            // ^4
        float r2 = dgap / dx;
        r2 = r2 * r2;            // ^2
        out[b * TT + t] = max_act * (1.0f - (r1 + r2));
    }
}

extern "C" void kernel_launch(void* const* d_in, const int* in_sizes, int n_in,
                              void* d_out, int out_size, void* d_ws, size_t ws_size,
                              hipStream_t stream) {
    const float* x      = (const float*)d_in[0];
    const float* state  = (const float*)d_in[1];
    const float* kern   = (const float*)d_in[2];
    const float* rec    = (const float*)d_in[3];
    const float* bias   = (const float*)d_in[4];
    const float* w_dv   = (const float*)d_in[5];
    const float* b_dv   = (const float*)d_in[6];
    const float* w_dt   = (const float*)d_in[7];
    const float* b_dt   = (const float*)d_in[8];
    const float* w_mj   = (const float*)d_in[9];
    const float* b_mj   = (const float*)d_in[10];
    const float* w_ma   = (const float*)d_in[11];
    const float* b_ma   = (const float*)d_in[12];
    const float* w_mi   = (const float*)d_in[13];
    const float* b_mi   = (const float*)d_in[14];
    float* out = (float*)d_out;

    encoder_kernel<<<BB, 64, 0, stream>>>(
        x, state, kern, rec, bias,
        w_dv, b_dv, w_dt, b_dt, w_mj, b_mj, w_ma, b_ma, w_mi, b_mi,
        out);
}